// Round 2
// baseline (1127.952 us; speedup 1.0000x reference)
//
#include <hip/hip_runtime.h>
#include <hip/hip_bf16.h>
#include <math.h>

// E=200000 edges, D=128, H=4 heads, N=50000 targets. seg = edge_index[1].

#define DIM 128
#define NHEAD 4
#define TM 32    // nodes per block in k5
#define WCH 16   // W2 rows per LDS chunk in k5 phase 2

// ---------------- K0: init — zero counts, permute W2, fold a-vectors ----------------
__global__ __launch_bounds__(256)
void k0_init(const float* __restrict__ Wsrc, const float* __restrict__ Wdst,
             const float* __restrict__ att_src, const float* __restrict__ att_dst,
             int* __restrict__ counts, float* __restrict__ a_src,
             float* __restrict__ a_dst, float* __restrict__ W2, int N)
{
    int zb = (N + 1 + 255) >> 8;
    int b = blockIdx.x, t = threadIdx.x;
    if (b < zb) {
        int i = (b << 8) + t;
        if (i <= N) counts[i] = 0;
    } else if (b < zb + 256) {
        // W2[(h*128+k)*128 + d] = Wsrc[k*512 + h*128 + d]
        int i = ((b - zb) << 8) + t;        // 0..65535
        int d = i & 127, j = i >> 7;        // j = h*128+k
        int h = j >> 7, k = j & 127;
        W2[i] = Wsrc[k * 512 + h * 128 + d];
    } else {
        int bb = b - zb - 256;              // 0..3 : 0,1 -> a_src ; 2,3 -> a_dst
        int p = ((bb & 1) << 8) + t;        // 0..511 (k,h) pair
        int k = p >> 2, h = p & 3;
        const float* W  = (bb < 2) ? Wsrc : Wdst;
        const float* at = (bb < 2) ? att_src : att_dst;
        float* outv     = (bb < 2) ? a_src : a_dst;
        float acc = 0.f;
        for (int d = 0; d < DIM; ++d)
            acc += W[k * 512 + h * 128 + d] * at[h * 128 + d];
        outv[k * 4 + h] = acc;              // layout [k][h], float4 per k
    }
}

// ---------------- K1: per-edge attention logits (wave per edge) ----------------
__global__ __launch_bounds__(256)
void k1_alpha(const float* __restrict__ src, const float* __restrict__ dst,
              const float* __restrict__ a_src, const float* __restrict__ a_dst,
              float* __restrict__ alpha, int E)
{
    int lane = threadIdx.x & 63;
    int wid  = (blockIdx.x * 256 + threadIdx.x) >> 6;
    int nw   = (gridDim.x * 256) >> 6;
    const float4* as4 = (const float4*)a_src;
    const float4* ad4 = (const float4*)a_dst;
    float4 as0 = as4[2 * lane], as1 = as4[2 * lane + 1];
    float4 ad0 = ad4[2 * lane], ad1 = ad4[2 * lane + 1];
    const float2* s2 = (const float2*)src;
    const float2* t2 = (const float2*)dst;
    for (int e = wid; e < E; e += nw) {
        float2 s = s2[e * 64 + lane];
        float2 u = t2[e * 64 + lane];
        float px = s.x*as0.x + s.y*as1.x + u.x*ad0.x + u.y*ad1.x;
        float py = s.x*as0.y + s.y*as1.y + u.x*ad0.y + u.y*ad1.y;
        float pz = s.x*as0.z + s.y*as1.z + u.x*ad0.z + u.y*ad1.z;
        float pw = s.x*as0.w + s.y*as1.w + u.x*ad0.w + u.y*ad1.w;
        for (int off = 32; off; off >>= 1) {
            px += __shfl_down(px, off, 64);
            py += __shfl_down(py, off, 64);
            pz += __shfl_down(pz, off, 64);
            pw += __shfl_down(pw, off, 64);
        }
        if (lane == 0) {
            float4 r;   // leaky_relu(x) = max(x, 0.2x)
            r.x = fmaxf(px, 0.2f * px);
            r.y = fmaxf(py, 0.2f * py);
            r.z = fmaxf(pz, 0.2f * pz);
            r.w = fmaxf(pw, 0.2f * pw);
            ((float4*)alpha)[e] = r;
        }
    }
}

// ---------------- K2: histogram ----------------
__global__ __launch_bounds__(256)
void k2_hist(const int* __restrict__ seg, int* __restrict__ counts, int E)
{
    int i = blockIdx.x * 256 + threadIdx.x;
    if (i < E) atomicAdd(&counts[seg[i]], 1);
}

// ---------------- K3a: per-block sums ----------------
__global__ __launch_bounds__(256)
void k3a_bsum(const int* __restrict__ counts, int* __restrict__ bsum, int N)
{
    __shared__ int ls[256];
    int t = threadIdx.x;
    int i = blockIdx.x * 256 + t;
    ls[t] = (i < N) ? counts[i] : 0;
    for (int off = 128; off; off >>= 1) {
        __syncthreads();
        if (t < off) ls[t] += ls[t + off];
    }
    if (t == 0) bsum[blockIdx.x] = ls[0];
}

// ---------------- K3b: scan block sums (single small block) ----------------
__global__ __launch_bounds__(256)
void k3b_bscan(int* __restrict__ bsum, int NB, int* __restrict__ countsN)
{
    __shared__ int ls[256];
    __shared__ int carry;
    int t = threadIdx.x;
    if (t == 0) carry = 0;
    __syncthreads();
    for (int base = 0; base < NB; base += 256) {
        int v = (base + t < NB) ? bsum[base + t] : 0;
        int orig = v;
        ls[t] = v;
        for (int off = 1; off < 256; off <<= 1) {
            __syncthreads();
            int u = (t >= off) ? ls[t - off] : 0;
            __syncthreads();
            ls[t] += u;
        }
        __syncthreads();
        if (base + t < NB) bsum[base + t] = carry + ls[t] - orig;  // exclusive
        __syncthreads();
        if (t == 0) carry += ls[255];
        __syncthreads();
    }
    if (t == 0) countsN[0] = carry;   // total = E
}

// ---------------- K3c: in-block exclusive scan + block offset ----------------
__global__ __launch_bounds__(256)
void k3c_scan(int* __restrict__ counts, int* __restrict__ cursor,
              const int* __restrict__ bsum, int N)
{
    __shared__ int ls[256];
    int t = threadIdx.x;
    int i = blockIdx.x * 256 + t;
    int v = (i < N) ? counts[i] : 0;
    int orig = v;
    ls[t] = v;
    for (int off = 1; off < 256; off <<= 1) {
        __syncthreads();
        int u = (t >= off) ? ls[t - off] : 0;
        __syncthreads();
        ls[t] += u;
    }
    __syncthreads();
    int excl = bsum[blockIdx.x] + ls[t] - orig;
    if (i < N) { counts[i] = excl; cursor[i] = excl; }
}

// ---------------- K4: scatter edge ids into CSR ----------------
__global__ __launch_bounds__(256)
void k4_scatter(const int* __restrict__ seg, int* __restrict__ cursor,
                int* __restrict__ elist, int E)
{
    int i = blockIdx.x * 256 + threadIdx.x;
    if (i < E) {
        int pos = atomicAdd(&cursor[seg[i]], 1);
        elist[pos] = i;
    }
}

// ---------------- K4b: per-node softmax stats (max, 0.25/denom) ----------------
__global__ __launch_bounds__(256)
void k4b_stats(const float4* __restrict__ alpha4, const int* __restrict__ offsets,
               const int* __restrict__ elist, float4* __restrict__ m4,
               float4* __restrict__ r4, int N)
{
    int n = blockIdx.x * 256 + threadIdx.x;
    if (n >= N) return;
    int off = offsets[n];
    int dg  = offsets[n + 1] - off;
    if (dg == 0) {
        m4[n] = make_float4(0.f, 0.f, 0.f, 0.f);
        r4[n] = make_float4(0.f, 0.f, 0.f, 0.f);
        return;
    }
    float m0 = -1e30f, m1 = -1e30f, m2 = -1e30f, m3 = -1e30f;
    for (int i = 0; i < dg; ++i) {
        float4 a = alpha4[elist[off + i]];
        m0 = fmaxf(m0, a.x); m1 = fmaxf(m1, a.y);
        m2 = fmaxf(m2, a.z); m3 = fmaxf(m3, a.w);
    }
    float s0 = 0.f, s1 = 0.f, s2 = 0.f, s3 = 0.f;
    for (int i = 0; i < dg; ++i) {
        float4 a = alpha4[elist[off + i]];
        s0 += __expf(a.x - m0); s1 += __expf(a.y - m1);
        s2 += __expf(a.z - m2); s3 += __expf(a.w - m3);
    }
    m4[n] = make_float4(m0, m1, m2, m3);
    // fold the head-mean 1/4 here
    r4[n] = make_float4(0.25f / (s0 + 1e-16f), 0.25f / (s1 + 1e-16f),
                        0.25f / (s2 + 1e-16f), 0.25f / (s3 + 1e-16f));
}

// ---------------- K4c: per-edge normalized weights ----------------
__global__ __launch_bounds__(256)
void k4c_wts(const float4* __restrict__ alpha4, const int* __restrict__ seg,
             const float4* __restrict__ m4, const float4* __restrict__ r4,
             float4* __restrict__ wbuf, int E)
{
    int e = blockIdx.x * 256 + threadIdx.x;
    if (e >= E) return;
    int s = seg[e];
    float4 a = alpha4[e], m = m4[s], r = r4[s];
    float4 w;
    w.x = __expf(a.x - m.x) * r.x;
    w.y = __expf(a.y - m.y) * r.y;
    w.z = __expf(a.z - m.z) * r.z;
    w.w = __expf(a.w - m.w) * r.w;
    wbuf[e] = w;
}

// ---------------- K5: edge-parallel aggregate (LDS atomics) + GEMM vs W2 ----------------
__global__ __launch_bounds__(256)
void k5_agg(const float* __restrict__ src, const float4* __restrict__ wbuf,
            const int* __restrict__ offsets, const int* __restrict__ elist,
            const int* __restrict__ seg, const float* __restrict__ W2,
            float* __restrict__ out, int N)
{
    __shared__ float  Gs[TM][512];    // 64 KB
    __shared__ float  Ws[WCH][128];   // 8 KB
    __shared__ int    Se[256];        // eid | nloc<<24
    __shared__ float4 Sw[256];        // 4 KB
    int t = threadIdx.x, lane = t & 63, wv = t >> 6;
    int nbase = blockIdx.x * TM;
    int nend = nbase + TM; if (nend > N) nend = N;

    for (int i = t; i < TM * 512; i += 256) ((float*)Gs)[i] = 0.f;
    int ebase = offsets[nbase];
    int eend  = offsets[nend];
    __syncthreads();

    // ---- phase 1: edge-parallel gather into Gs via LDS atomics ----
    for (int tb = ebase; tb < eend; tb += 256) {
        int ne = eend - tb; if (ne > 256) ne = 256;
        if (t < ne) {
            int e = elist[tb + t];
            Se[t] = e | ((seg[e] - nbase) << 24);
            Sw[t] = wbuf[e];
        }
        __syncthreads();
        int c0 = (ne * wv) >> 2, c1 = (ne * (wv + 1)) >> 2;
        for (int i = c0; i < c1; i += 2) {
            int pk0 = Se[i];
            float4 w0 = Sw[i];
            int e0 = pk0 & 0xFFFFFF, n0 = pk0 >> 24;
            float x0 = src[e0 * DIM + lane];
            float y0 = src[e0 * DIM + 64 + lane];
            int has1 = (i + 1 < c1);
            int i1 = has1 ? i + 1 : i;
            int pk1 = Se[i1];
            float4 w1 = Sw[i1];
            if (!has1) w1 = make_float4(0.f, 0.f, 0.f, 0.f);
            int e1 = pk1 & 0xFFFFFF, n1 = pk1 >> 24;
            float x1 = src[e1 * DIM + lane];
            float y1 = src[e1 * DIM + 64 + lane];

            float* g0 = &Gs[n0][lane];
            atomicAdd(g0 +   0, w0.x * x0); atomicAdd(g0 + 128, w0.y * x0);
            atomicAdd(g0 + 256, w0.z * x0); atomicAdd(g0 + 384, w0.w * x0);
            atomicAdd(g0 +  64, w0.x * y0); atomicAdd(g0 + 192, w0.y * y0);
            atomicAdd(g0 + 320, w0.z * y0); atomicAdd(g0 + 448, w0.w * y0);
            float* g1 = &Gs[n1][lane];
            atomicAdd(g1 +   0, w1.x * x1); atomicAdd(g1 + 128, w1.y * x1);
            atomicAdd(g1 + 256, w1.z * x1); atomicAdd(g1 + 384, w1.w * x1);
            atomicAdd(g1 +  64, w1.x * y1); atomicAdd(g1 + 192, w1.y * y1);
            atomicAdd(g1 + 320, w1.z * y1); atomicAdd(g1 + 448, w1.w * y1);
        }
        __syncthreads();
    }

    // ---- phase 2: out = Gs @ W2 (1/4 already folded into weights) ----
    float acc[8][2];
    #pragma unroll
    for (int j = 0; j < 8; ++j) { acc[j][0] = 0.f; acc[j][1] = 0.f; }
    int nloc0 = wv * 8;
    for (int kc = 0; kc < 512; kc += WCH) {
        for (int i = t; i < WCH * 128; i += 256) {
            int r = i >> 7, d = i & 127;
            Ws[r][d] = W2[(kc + r) * 128 + d];
        }
        __syncthreads();
        #pragma unroll
        for (int kq = 0; kq < WCH / 4; ++kq) {
            float w00 = Ws[kq*4+0][lane], w01 = Ws[kq*4+0][64+lane];
            float w10 = Ws[kq*4+1][lane], w11 = Ws[kq*4+1][64+lane];
            float w20 = Ws[kq*4+2][lane], w21 = Ws[kq*4+2][64+lane];
            float w30 = Ws[kq*4+3][lane], w31 = Ws[kq*4+3][64+lane];
            #pragma unroll
            for (int j = 0; j < 8; ++j) {
                float4 g = *(const float4*)&Gs[nloc0 + j][kc + kq*4];
                acc[j][0] += g.x*w00 + g.y*w10 + g.z*w20 + g.w*w30;
                acc[j][1] += g.x*w01 + g.y*w11 + g.z*w21 + g.w*w31;
            }
        }
        __syncthreads();
    }
    #pragma unroll
    for (int j = 0; j < 8; ++j) {
        int n = nbase + nloc0 + j;
        if (n < N) {
            out[n * DIM + lane]      = acc[j][0];
            out[n * DIM + 64 + lane] = acc[j][1];
        }
    }
}

extern "C" void kernel_launch(void* const* d_in, const int* in_sizes, int n_in,
                              void* d_out, int out_size, void* d_ws, size_t ws_size,
                              hipStream_t stream)
{
    const float* src     = (const float*)d_in[0];
    const float* dst     = (const float*)d_in[1];
    const int*   eidx    = (const int*)d_in[2];
    const float* Wsrc    = (const float*)d_in[3];
    const float* Wdst    = (const float*)d_in[4];
    const float* att_src = (const float*)d_in[5];
    const float* att_dst = (const float*)d_in[6];

    int E = in_sizes[0] / DIM;          // 200000
    int N = out_size / DIM;             // 50000
    const int* seg = eidx + E;          // edge_index[1]
    int NB = (N + 255) >> 8;

    char* ws = (char*)d_ws;
    size_t o = 0;
    auto alloc = [&](size_t bytes) { size_t r = o; o += (bytes + 255) & ~(size_t)255; return r; };
    int*    counts = (int*)   (ws + alloc((size_t)(N + 1) * 4)); // becomes offsets
    int*    cursor = (int*)   (ws + alloc((size_t)N * 4));
    int*    elist  = (int*)   (ws + alloc((size_t)E * 4));
    int*    bsum   = (int*)   (ws + alloc((size_t)NB * 4));
    float*  a_src  = (float*) (ws + alloc(512 * 4));
    float*  a_dst  = (float*) (ws + alloc(512 * 4));
    float*  W2     = (float*) (ws + alloc(65536 * 4));
    float*  alpha  = (float*) (ws + alloc((size_t)E * NHEAD * 4));
    float4* wbuf   = (float4*)(ws + alloc((size_t)E * 16));
    float4* m4     = (float4*)(ws + alloc((size_t)N * 16));
    float4* r4     = (float4*)(ws + alloc((size_t)N * 16));
    (void)ws_size; (void)n_in;

    int zb = (N + 1 + 255) >> 8;
    k0_init<<<zb + 256 + 4, 256, 0, stream>>>(Wsrc, Wdst, att_src, att_dst,
                                              counts, a_src, a_dst, W2, N);
    k1_alpha<<<1024, 256, 0, stream>>>(src, dst, a_src, a_dst, alpha, E);
    k2_hist<<<(E + 255) / 256, 256, 0, stream>>>(seg, counts, E);
    k3a_bsum<<<NB, 256, 0, stream>>>(counts, bsum, N);
    k3b_bscan<<<1, 256, 0, stream>>>(bsum, NB, counts + N);
    k3c_scan<<<NB, 256, 0, stream>>>(counts, cursor, bsum, N);
    k4_scatter<<<(E + 255) / 256, 256, 0, stream>>>(seg, cursor, elist, E);
    k4b_stats<<<(N + 255) / 256, 256, 0, stream>>>((const float4*)alpha, counts,
                                                   elist, m4, r4, N);
    k4c_wts<<<(E + 255) / 256, 256, 0, stream>>>((const float4*)alpha, seg,
                                                 m4, r4, wbuf, E);
    k5_agg<<<(N + TM - 1) / TM, 256, 0, stream>>>(src, wbuf, counts, elist, seg,
                                                  W2, (float*)d_out, N);
}

// Round 3
// 806.958 us; speedup vs baseline: 1.3978x; 1.3978x over previous
//
#include <hip/hip_runtime.h>
#include <hip/hip_bf16.h>
#include <math.h>

// E=200000 edges, D=128, H=4 heads, N=50000 targets. seg = edge_index[1].
// Pipeline:
//   k0  : zero {counts, maxkey, denom}, permute W2, fold attention vectors
//   k1  : per-edge logits alpha[E,4] + leaky; fused segment-max (uint-encoded
//         atomicMax) + degree histogram
//   k3a/k3b/k3c : hierarchical exclusive scan of counts -> CSR offsets (+cursor)
//   k4  : scatter edge ids to elist; p[e]=exp(a-m[seg]) stored in-place over
//         alpha; fused denom atomicAdd
//   k5a : per-wave register aggregation  G[n,512] = sum_e p*src  (NO LDS)
//   k6  : out = G @ W2  (fp32, no LDS, W2 from L2, G float4 broadcasts)

#define DIM 128

__device__ __forceinline__ unsigned enc_f(float f) {
    unsigned b = __float_as_uint(f);
    return (b & 0x80000000u) ? ~b : (b | 0x80000000u);
}
__device__ __forceinline__ float dec_f(unsigned k) {
    return __uint_as_float((k & 0x80000000u) ? (k & 0x7FFFFFFFu) : ~k);
}

// ---------------- K0: zero workspace zone, permute W2, fold a-vectors ----------------
__global__ __launch_bounds__(256)
void k0_init(const float* __restrict__ Wsrc, const float* __restrict__ Wdst,
             const float* __restrict__ att_src, const float* __restrict__ att_dst,
             int* __restrict__ zbase, int zn,
             float* __restrict__ a_src, float* __restrict__ a_dst,
             float* __restrict__ W2, int zb)
{
    int b = blockIdx.x, t = threadIdx.x;
    if (b < zb) {
        int i = (b << 8) + t;
        if (i < zn) zbase[i] = 0;
    } else if (b < zb + 256) {
        // W2[(h*128+k)*128 + d] = Wsrc[k*512 + h*128 + d]
        int i = ((b - zb) << 8) + t;        // 0..65535
        int d = i & 127, j = i >> 7;        // j = h*128+k
        int h = j >> 7, k = j & 127;
        W2[i] = Wsrc[k * 512 + h * 128 + d];
    } else {
        int bb = b - zb - 256;              // 0..3
        int p = ((bb & 1) << 8) + t;        // 0..511 (k,h)
        int k = p >> 2, h = p & 3;
        const float* W  = (bb < 2) ? Wsrc : Wdst;
        const float* at = (bb < 2) ? att_src : att_dst;
        float* outv     = (bb < 2) ? a_src : a_dst;
        float acc = 0.f;
        for (int d = 0; d < DIM; ++d)
            acc += W[k * 512 + h * 128 + d] * at[h * 128 + d];
        outv[k * 4 + h] = acc;              // [k][h]
    }
}

// ---------------- K1: logits + leaky + fused segmax/histogram ----------------
__global__ __launch_bounds__(256)
void k1_alpha(const float* __restrict__ src, const float* __restrict__ dst,
              const float* __restrict__ a_src, const float* __restrict__ a_dst,
              const int* __restrict__ seg, float* __restrict__ alpha,
              unsigned* __restrict__ maxkey, int* __restrict__ counts, int E)
{
    int lane = threadIdx.x & 63;
    int wid  = (blockIdx.x * 256 + threadIdx.x) >> 6;
    int nw   = (gridDim.x * 256) >> 6;
    const float4* as4 = (const float4*)a_src;
    const float4* ad4 = (const float4*)a_dst;
    float4 as0 = as4[2 * lane], as1 = as4[2 * lane + 1];
    float4 ad0 = ad4[2 * lane], ad1 = ad4[2 * lane + 1];
    const float2* s2 = (const float2*)src;
    const float2* t2 = (const float2*)dst;
    for (int e = wid; e < E; e += nw) {
        float2 s = s2[e * 64 + lane];
        float2 u = t2[e * 64 + lane];
        float px = s.x*as0.x + s.y*as1.x + u.x*ad0.x + u.y*ad1.x;
        float py = s.x*as0.y + s.y*as1.y + u.x*ad0.y + u.y*ad1.y;
        float pz = s.x*as0.z + s.y*as1.z + u.x*ad0.z + u.y*ad1.z;
        float pw = s.x*as0.w + s.y*as1.w + u.x*ad0.w + u.y*ad1.w;
        for (int off = 32; off; off >>= 1) {
            px += __shfl_down(px, off, 64);
            py += __shfl_down(py, off, 64);
            pz += __shfl_down(pz, off, 64);
            pw += __shfl_down(pw, off, 64);
        }
        if (lane == 0) {
            float4 r;   // leaky_relu
            r.x = fmaxf(px, 0.2f * px);
            r.y = fmaxf(py, 0.2f * py);
            r.z = fmaxf(pz, 0.2f * pz);
            r.w = fmaxf(pw, 0.2f * pw);
            ((float4*)alpha)[e] = r;
            int sg = seg[e];
            atomicMax(&maxkey[sg * 4 + 0], enc_f(r.x));
            atomicMax(&maxkey[sg * 4 + 1], enc_f(r.y));
            atomicMax(&maxkey[sg * 4 + 2], enc_f(r.z));
            atomicMax(&maxkey[sg * 4 + 3], enc_f(r.w));
            atomicAdd(&counts[sg], 1);
        }
    }
}

// ---------------- K3a: per-block sums ----------------
__global__ __launch_bounds__(256)
void k3a_bsum(const int* __restrict__ counts, int* __restrict__ bsum, int N)
{
    __shared__ int ls[256];
    int t = threadIdx.x;
    int i = blockIdx.x * 256 + t;
    ls[t] = (i < N) ? counts[i] : 0;
    for (int off = 128; off; off >>= 1) {
        __syncthreads();
        if (t < off) ls[t] += ls[t + off];
    }
    if (t == 0) bsum[blockIdx.x] = ls[0];
}

// ---------------- K3b: scan block sums ----------------
__global__ __launch_bounds__(256)
void k3b_bscan(int* __restrict__ bsum, int NB, int* __restrict__ countsN)
{
    __shared__ int ls[256];
    __shared__ int carry;
    int t = threadIdx.x;
    if (t == 0) carry = 0;
    __syncthreads();
    for (int base = 0; base < NB; base += 256) {
        int v = (base + t < NB) ? bsum[base + t] : 0;
        int orig = v;
        ls[t] = v;
        for (int off = 1; off < 256; off <<= 1) {
            __syncthreads();
            int u = (t >= off) ? ls[t - off] : 0;
            __syncthreads();
            ls[t] += u;
        }
        __syncthreads();
        if (base + t < NB) bsum[base + t] = carry + ls[t] - orig;
        __syncthreads();
        if (t == 0) carry += ls[255];
        __syncthreads();
    }
    if (t == 0) countsN[0] = carry;   // offsets[N] = E
}

// ---------------- K3c: in-block scan + block offset ----------------
__global__ __launch_bounds__(256)
void k3c_scan(int* __restrict__ counts, int* __restrict__ cursor,
              const int* __restrict__ bsum, int N)
{
    __shared__ int ls[256];
    int t = threadIdx.x;
    int i = blockIdx.x * 256 + t;
    int v = (i < N) ? counts[i] : 0;
    int orig = v;
    ls[t] = v;
    for (int off = 1; off < 256; off <<= 1) {
        __syncthreads();
        int u = (t >= off) ? ls[t - off] : 0;
        __syncthreads();
        ls[t] += u;
    }
    __syncthreads();
    int excl = bsum[blockIdx.x] + ls[t] - orig;
    if (i < N) { counts[i] = excl; cursor[i] = excl; }
}

// ---------------- K4: scatter + p=exp(a-m) in-place + denom atomics ----------------
__global__ __launch_bounds__(256)
void k4_scatter(const int* __restrict__ seg, int* __restrict__ cursor,
                int* __restrict__ elist, float4* __restrict__ alpha4,
                const unsigned* __restrict__ maxkey, float* __restrict__ denom, int E)
{
    int e = blockIdx.x * 256 + threadIdx.x;
    if (e >= E) return;
    int sg = seg[e];
    int pos = atomicAdd(&cursor[sg], 1);
    elist[pos] = e;
    float4 a = alpha4[e];
    uint4 mk = ((const uint4*)maxkey)[sg];
    float4 p;
    p.x = __expf(a.x - dec_f(mk.x));
    p.y = __expf(a.y - dec_f(mk.y));
    p.z = __expf(a.z - dec_f(mk.z));
    p.w = __expf(a.w - dec_f(mk.w));
    alpha4[e] = p;                      // reuse buffer as p
    atomicAdd(&denom[sg * 4 + 0], p.x);
    atomicAdd(&denom[sg * 4 + 1], p.y);
    atomicAdd(&denom[sg * 4 + 2], p.z);
    atomicAdd(&denom[sg * 4 + 3], p.w);
}

// ---------------- K5a: per-wave register aggregation -> G[N,512] ----------------
__global__ __launch_bounds__(256)
void k5a_agg(const float* __restrict__ src, const float4* __restrict__ pbuf,
             const int* __restrict__ offsets, const int* __restrict__ elist,
             const float* __restrict__ denom, float* __restrict__ G, int N)
{
    int t = threadIdx.x, lane = t & 63, wv = t >> 6;
    int nb = (blockIdx.x * 4 + wv) * 8;
    if (nb >= N) return;
    const float2* s2 = (const float2*)src;

    int offs[9];
    #pragma unroll
    for (int jj = 0; jj <= 8; ++jj) {
        int idx = nb + jj; if (idx > N) idx = N;
        offs[jj] = offsets[idx];
    }

    int jmax = N - nb; if (jmax > 8) jmax = 8;
    for (int j = 0; j < jmax; ++j) {
        int n = nb + j;
        int s = offs[j], eEnd = offs[j + 1];
        float4 dnm = ((const float4*)denom)[n];
        float a0x=0.f,a0y=0.f,a1x=0.f,a1y=0.f,a2x=0.f,a2y=0.f,a3x=0.f,a3y=0.f;
        for (int i = s; i < eEnd; i += 4) {
            int cnt = eEnd - i;
            int last = eEnd - 1;
            int e0 = __builtin_amdgcn_readfirstlane(elist[i]);
            int e1 = __builtin_amdgcn_readfirstlane(elist[(cnt > 1) ? i + 1 : last]);
            int e2 = __builtin_amdgcn_readfirstlane(elist[(cnt > 2) ? i + 2 : last]);
            int e3 = __builtin_amdgcn_readfirstlane(elist[(cnt > 3) ? i + 3 : last]);
            float m1 = (cnt > 1) ? 1.f : 0.f;
            float m2 = (cnt > 2) ? 1.f : 0.f;
            float m3 = (cnt > 3) ? 1.f : 0.f;
            float4 p0 = pbuf[e0], p1 = pbuf[e1], p2 = pbuf[e2], p3 = pbuf[e3];
            float2 x0 = s2[e0 * 64 + lane];
            float2 x1 = s2[e1 * 64 + lane];
            float2 x2 = s2[e2 * 64 + lane];
            float2 x3 = s2[e3 * 64 + lane];
            a0x += p0.x*x0.x; a0y += p0.x*x0.y;
            a1x += p0.y*x0.x; a1y += p0.y*x0.y;
            a2x += p0.z*x0.x; a2y += p0.z*x0.y;
            a3x += p0.w*x0.x; a3y += p0.w*x0.y;
            p1.x *= m1; p1.y *= m1; p1.z *= m1; p1.w *= m1;
            a0x += p1.x*x1.x; a0y += p1.x*x1.y;
            a1x += p1.y*x1.x; a1y += p1.y*x1.y;
            a2x += p1.z*x1.x; a2y += p1.z*x1.y;
            a3x += p1.w*x1.x; a3y += p1.w*x1.y;
            p2.x *= m2; p2.y *= m2; p2.z *= m2; p2.w *= m2;
            a0x += p2.x*x2.x; a0y += p2.x*x2.y;
            a1x += p2.y*x2.x; a1y += p2.y*x2.y;
            a2x += p2.z*x2.x; a2y += p2.z*x2.y;
            a3x += p2.w*x2.x; a3y += p2.w*x2.y;
            p3.x *= m3; p3.y *= m3; p3.z *= m3; p3.w *= m3;
            a0x += p3.x*x3.x; a0y += p3.x*x3.y;
            a1x += p3.y*x3.x; a1y += p3.y*x3.y;
            a2x += p3.z*x3.x; a2y += p3.z*x3.y;
            a3x += p3.w*x3.x; a3y += p3.w*x3.y;
        }
        // normalize (deg==0 -> acc==0 -> store exact zeros)
        float r0 = 0.25f / (dnm.x + 1e-16f);
        float r1 = 0.25f / (dnm.y + 1e-16f);
        float r2 = 0.25f / (dnm.z + 1e-16f);
        float r3 = 0.25f / (dnm.w + 1e-16f);
        float2* grow = (float2*)(G + (size_t)n * 512);
        grow[0 * 64 + lane] = make_float2(a0x * r0, a0y * r0);
        grow[1 * 64 + lane] = make_float2(a1x * r1, a1y * r1);
        grow[2 * 64 + lane] = make_float2(a2x * r2, a2y * r2);
        grow[3 * 64 + lane] = make_float2(a3x * r3, a3y * r3);
    }
}

// ---------------- K6: out = G @ W2 (no LDS; W2 from L2, G broadcast) ----------------
__global__ __launch_bounds__(256)
void k6_gemm(const float* __restrict__ G, const float* __restrict__ W2,
             float* __restrict__ out, int N)
{
    int t = threadIdx.x, lane = t & 63, wv = t >> 6;
    int rbase = blockIdx.x * 64 + wv * 16;

    float accA[16], accB[16];
    #pragma unroll
    for (int j = 0; j < 16; ++j) { accA[j] = 0.f; accB[j] = 0.f; }

    int rows[16];
    #pragma unroll
    for (int j = 0; j < 16; ++j) {
        int r = rbase + j; if (r >= N) r = N - 1;
        rows[j] = r;
    }

    for (int k0 = 0; k0 < 512; k0 += 4) {
        const float* w = W2 + (size_t)k0 * 128;
        float wa0 = w[lane],           wb0 = w[64 + lane];
        float wa1 = w[128 + lane],     wb1 = w[192 + lane];
        float wa2 = w[256 + lane],     wb2 = w[320 + lane];
        float wa3 = w[384 + lane],     wb3 = w[448 + lane];
        #pragma unroll
        for (int j = 0; j < 16; ++j) {
            float4 g = *(const float4*)(G + (size_t)rows[j] * 512 + k0);
            accA[j] += g.x*wa0 + g.y*wa1 + g.z*wa2 + g.w*wa3;
            accB[j] += g.x*wb0 + g.y*wb1 + g.z*wb2 + g.w*wb3;
        }
    }
    #pragma unroll
    for (int j = 0; j < 16; ++j) {
        int n = rbase + j;
        if (n < N) {
            out[(size_t)n * 128 + lane]      = accA[j];
            out[(size_t)n * 128 + 64 + lane] = accB[j];
        }
    }
}

extern "C" void kernel_launch(void* const* d_in, const int* in_sizes, int n_in,
                              void* d_out, int out_size, void* d_ws, size_t ws_size,
                              hipStream_t stream)
{
    const float* src     = (const float*)d_in[0];
    const float* dst     = (const float*)d_in[1];
    const int*   eidx    = (const int*)d_in[2];
    const float* Wsrc    = (const float*)d_in[3];
    const float* Wdst    = (const float*)d_in[4];
    const float* att_src = (const float*)d_in[5];
    const float* att_dst = (const float*)d_in[6];

    int E = in_sizes[0] / DIM;          // 200000
    int N = out_size / DIM;             // 50000
    const int* seg = eidx + E;          // edge_index[1]
    int NB = (N + 255) >> 8;

    char* ws = (char*)d_ws;
    size_t o = 0;
    auto alloc = [&](size_t bytes) { size_t r = o; o += (bytes + 255) & ~(size_t)255; return r; };
    // contiguous zero-zone: counts | maxkey | denom
    size_t counts_off = alloc((size_t)(N + 1) * 4);
    size_t maxkey_off = alloc((size_t)N * 4 * 4);
    size_t denom_off  = alloc((size_t)N * 4 * 4);
    int*      counts = (int*)     (ws + counts_off);   // becomes offsets
    unsigned* maxkey = (unsigned*)(ws + maxkey_off);
    float*    denom  = (float*)   (ws + denom_off);
    int zn = (int)((denom_off + (size_t)N * 16 - counts_off) / 4);

    int*    cursor = (int*)   (ws + alloc((size_t)N * 4));
    int*    elist  = (int*)   (ws + alloc((size_t)E * 4));
    int*    bsum   = (int*)   (ws + alloc((size_t)NB * 4));
    float*  a_src  = (float*) (ws + alloc(512 * 4));
    float*  a_dst  = (float*) (ws + alloc(512 * 4));
    float*  W2     = (float*) (ws + alloc(65536 * 4));
    float*  alpha  = (float*) (ws + alloc((size_t)E * 16));   // becomes p
    float*  G      = (float*) (ws + alloc((size_t)N * 512 * 4)); // 102.4 MB
    (void)ws_size; (void)n_in;

    int zb = (zn + 255) >> 8;
    k0_init<<<zb + 256 + 4, 256, 0, stream>>>(Wsrc, Wdst, att_src, att_dst,
                                              (int*)(ws + counts_off), zn,
                                              a_src, a_dst, W2, zb);
    k1_alpha<<<1024, 256, 0, stream>>>(src, dst, a_src, a_dst, seg,
                                       alpha, maxkey, counts, E);
    k3a_bsum<<<NB, 256, 0, stream>>>(counts, bsum, N);
    k3b_bscan<<<1, 256, 0, stream>>>(bsum, NB, counts + N);
    k3c_scan<<<NB, 256, 0, stream>>>(counts, cursor, bsum, N);
    k4_scatter<<<(E + 255) / 256, 256, 0, stream>>>(seg, cursor, elist,
                                                    (float4*)alpha, maxkey, denom, E);
    k5a_agg<<<(N + 31) / 32, 256, 0, stream>>>(src, (const float4*)alpha,
                                               counts, elist, denom, G, N);
    k6_gemm<<<(N + 63) / 64, 256, 0, stream>>>(G, W2, (float*)d_out, N);
}

// Round 4
// 405.770 us; speedup vs baseline: 2.7798x; 1.9887x over previous
//
#include <hip/hip_runtime.h>
#include <hip/hip_bf16.h>
#include <math.h>

// E=200000 edges, D=128, H=4 heads, N=50000 targets. seg = edge_index[1].
// Pipeline:
//   k0  : zero {counts, maxkey, denom}, build W2T (bf16, [128][512]), fold a-vecs
//   k1  : per-edge logits alpha[E,4] + leaky; fused segment-max + degree hist
//   k3a/k3b/k3c : hierarchical exclusive scan -> CSR offsets (+cursor)
//   k4  : scatter edge ids; p=exp(a-m[seg]) in-place; denom atomics
//   k5a : per-wave register aggregation -> G16[N,512] bf16 (normalized, /4 folded)
//   k6  : out = G16 @ W2T^T via mfma_f32_16x16x32_bf16 (LDS-free)

#define DIM 128

typedef __attribute__((ext_vector_type(8))) short short8;
typedef __attribute__((ext_vector_type(4))) float f32x4;

__device__ __forceinline__ unsigned enc_f(float f) {
    unsigned b = __float_as_uint(f);
    return (b & 0x80000000u) ? ~b : (b | 0x80000000u);
}
__device__ __forceinline__ float dec_f(unsigned k) {
    return __uint_as_float((k & 0x80000000u) ? (k & 0x7FFFFFFFu) : ~k);
}
__device__ __forceinline__ unsigned short f2bf(float x) {
    __hip_bfloat16 b = __float2bfloat16(x);
    return *(unsigned short*)&b;
}

// ---------------- K0: zero zone, build W2T bf16, fold a-vectors ----------------
__global__ __launch_bounds__(256)
void k0_init(const float* __restrict__ Wsrc, const float* __restrict__ Wdst,
             const float* __restrict__ att_src, const float* __restrict__ att_dst,
             int* __restrict__ zbase, int zn,
             float* __restrict__ a_src, float* __restrict__ a_dst,
             unsigned short* __restrict__ W2T, int zb)
{
    int b = blockIdx.x, t = threadIdx.x;
    if (b < zb) {
        int i = (b << 8) + t;
        if (i < zn) zbase[i] = 0;
    } else if (b < zb + 256) {
        // W2T[d][j] = W2[j][d] = Wsrc[k*512 + h*128 + d],  j = h*128+k
        int i = ((b - zb) << 8) + t;        // 0..65535 = d*512 + j
        int d = i >> 9, j = i & 511;
        int h = j >> 7, k = j & 127;
        W2T[i] = f2bf(Wsrc[k * 512 + h * 128 + d]);
    } else {
        int bb = b - zb - 256;              // 0..3
        int p = ((bb & 1) << 8) + t;        // 0..511 (k,h)
        int k = p >> 2, h = p & 3;
        const float* W  = (bb < 2) ? Wsrc : Wdst;
        const float* at = (bb < 2) ? att_src : att_dst;
        float* outv     = (bb < 2) ? a_src : a_dst;
        float acc = 0.f;
        for (int d = 0; d < DIM; ++d)
            acc += W[k * 512 + h * 128 + d] * at[h * 128 + d];
        outv[k * 4 + h] = acc;              // [k][h]
    }
}

// ---------------- K1: logits + leaky + fused segmax/histogram ----------------
__global__ __launch_bounds__(256)
void k1_alpha(const float* __restrict__ src, const float* __restrict__ dst,
              const float* __restrict__ a_src, const float* __restrict__ a_dst,
              const int* __restrict__ seg, float* __restrict__ alpha,
              unsigned* __restrict__ maxkey, int* __restrict__ counts, int E)
{
    int lane = threadIdx.x & 63;
    int wid  = (blockIdx.x * 256 + threadIdx.x) >> 6;
    int nw   = (gridDim.x * 256) >> 6;
    const float4* as4 = (const float4*)a_src;
    const float4* ad4 = (const float4*)a_dst;
    float4 as0 = as4[2 * lane], as1 = as4[2 * lane + 1];
    float4 ad0 = ad4[2 * lane], ad1 = ad4[2 * lane + 1];
    const float2* s2 = (const float2*)src;
    const float2* t2 = (const float2*)dst;
    for (int e = wid; e < E; e += nw) {
        float2 s = s2[e * 64 + lane];
        float2 u = t2[e * 64 + lane];
        float px = s.x*as0.x + s.y*as1.x + u.x*ad0.x + u.y*ad1.x;
        float py = s.x*as0.y + s.y*as1.y + u.x*ad0.y + u.y*ad1.y;
        float pz = s.x*as0.z + s.y*as1.z + u.x*ad0.z + u.y*ad1.z;
        float pw = s.x*as0.w + s.y*as1.w + u.x*ad0.w + u.y*ad1.w;
        for (int off = 32; off; off >>= 1) {
            px += __shfl_down(px, off, 64);
            py += __shfl_down(py, off, 64);
            pz += __shfl_down(pz, off, 64);
            pw += __shfl_down(pw, off, 64);
        }
        if (lane == 0) {
            float4 r;   // leaky_relu
            r.x = fmaxf(px, 0.2f * px);
            r.y = fmaxf(py, 0.2f * py);
            r.z = fmaxf(pz, 0.2f * pz);
            r.w = fmaxf(pw, 0.2f * pw);
            ((float4*)alpha)[e] = r;
            int sg = seg[e];
            atomicMax(&maxkey[sg * 4 + 0], enc_f(r.x));
            atomicMax(&maxkey[sg * 4 + 1], enc_f(r.y));
            atomicMax(&maxkey[sg * 4 + 2], enc_f(r.z));
            atomicMax(&maxkey[sg * 4 + 3], enc_f(r.w));
            atomicAdd(&counts[sg], 1);
        }
    }
}

// ---------------- K3a: per-block sums ----------------
__global__ __launch_bounds__(256)
void k3a_bsum(const int* __restrict__ counts, int* __restrict__ bsum, int N)
{
    __shared__ int ls[256];
    int t = threadIdx.x;
    int i = blockIdx.x * 256 + t;
    ls[t] = (i < N) ? counts[i] : 0;
    for (int off = 128; off; off >>= 1) {
        __syncthreads();
        if (t < off) ls[t] += ls[t + off];
    }
    if (t == 0) bsum[blockIdx.x] = ls[0];
}

// ---------------- K3b: scan block sums ----------------
__global__ __launch_bounds__(256)
void k3b_bscan(int* __restrict__ bsum, int NB, int* __restrict__ countsN)
{
    __shared__ int ls[256];
    __shared__ int carry;
    int t = threadIdx.x;
    if (t == 0) carry = 0;
    __syncthreads();
    for (int base = 0; base < NB; base += 256) {
        int v = (base + t < NB) ? bsum[base + t] : 0;
        int orig = v;
        ls[t] = v;
        for (int off = 1; off < 256; off <<= 1) {
            __syncthreads();
            int u = (t >= off) ? ls[t - off] : 0;
            __syncthreads();
            ls[t] += u;
        }
        __syncthreads();
        if (base + t < NB) bsum[base + t] = carry + ls[t] - orig;
        __syncthreads();
        if (t == 0) carry += ls[255];
        __syncthreads();
    }
    if (t == 0) countsN[0] = carry;   // offsets[N] = E
}

// ---------------- K3c: in-block scan + block offset ----------------
__global__ __launch_bounds__(256)
void k3c_scan(int* __restrict__ counts, int* __restrict__ cursor,
              const int* __restrict__ bsum, int N)
{
    __shared__ int ls[256];
    int t = threadIdx.x;
    int i = blockIdx.x * 256 + t;
    int v = (i < N) ? counts[i] : 0;
    int orig = v;
    ls[t] = v;
    for (int off = 1; off < 256; off <<= 1) {
        __syncthreads();
        int u = (t >= off) ? ls[t - off] : 0;
        __syncthreads();
        ls[t] += u;
    }
    __syncthreads();
    int excl = bsum[blockIdx.x] + ls[t] - orig;
    if (i < N) { counts[i] = excl; cursor[i] = excl; }
}

// ---------------- K4: scatter + p=exp(a-m) in-place + denom atomics ----------------
__global__ __launch_bounds__(256)
void k4_scatter(const int* __restrict__ seg, int* __restrict__ cursor,
                int* __restrict__ elist, float4* __restrict__ alpha4,
                const unsigned* __restrict__ maxkey, float* __restrict__ denom, int E)
{
    int e = blockIdx.x * 256 + threadIdx.x;
    if (e >= E) return;
    int sg = seg[e];
    int pos = atomicAdd(&cursor[sg], 1);
    elist[pos] = e;
    float4 a = alpha4[e];
    uint4 mk = ((const uint4*)maxkey)[sg];
    float4 p;
    p.x = __expf(a.x - dec_f(mk.x));
    p.y = __expf(a.y - dec_f(mk.y));
    p.z = __expf(a.z - dec_f(mk.z));
    p.w = __expf(a.w - dec_f(mk.w));
    alpha4[e] = p;                      // reuse buffer as p
    atomicAdd(&denom[sg * 4 + 0], p.x);
    atomicAdd(&denom[sg * 4 + 1], p.y);
    atomicAdd(&denom[sg * 4 + 2], p.z);
    atomicAdd(&denom[sg * 4 + 3], p.w);
}

// ---------------- K5a: per-wave register aggregation -> G16[N,512] bf16 ----------------
__global__ __launch_bounds__(256)
void k5a_agg(const float* __restrict__ src, const float4* __restrict__ pbuf,
             const int* __restrict__ offsets, const int* __restrict__ elist,
             const float* __restrict__ denom, unsigned short* __restrict__ G16, int N)
{
    int t = threadIdx.x, lane = t & 63, wv = t >> 6;
    int nb = (blockIdx.x * 4 + wv) * 8;
    if (nb >= N) return;
    const float2* s2 = (const float2*)src;

    int offs[9];
    #pragma unroll
    for (int jj = 0; jj <= 8; ++jj) {
        int idx = nb + jj; if (idx > N) idx = N;
        offs[jj] = offsets[idx];
    }

    int jmax = N - nb; if (jmax > 8) jmax = 8;
    for (int j = 0; j < jmax; ++j) {
        int n = nb + j;
        int s = offs[j], eEnd = offs[j + 1];
        float4 dnm = ((const float4*)denom)[n];
        float a0x=0.f,a0y=0.f,a1x=0.f,a1y=0.f,a2x=0.f,a2y=0.f,a3x=0.f,a3y=0.f;
        for (int i = s; i < eEnd; i += 4) {
            int cnt = eEnd - i;
            int last = eEnd - 1;
            int e0 = __builtin_amdgcn_readfirstlane(elist[i]);
            int e1 = __builtin_amdgcn_readfirstlane(elist[(cnt > 1) ? i + 1 : last]);
            int e2 = __builtin_amdgcn_readfirstlane(elist[(cnt > 2) ? i + 2 : last]);
            int e3 = __builtin_amdgcn_readfirstlane(elist[(cnt > 3) ? i + 3 : last]);
            float m1 = (cnt > 1) ? 1.f : 0.f;
            float m2 = (cnt > 2) ? 1.f : 0.f;
            float m3 = (cnt > 3) ? 1.f : 0.f;
            float4 p0 = pbuf[e0], p1 = pbuf[e1], p2 = pbuf[e2], p3 = pbuf[e3];
            float2 x0 = s2[e0 * 64 + lane];
            float2 x1 = s2[e1 * 64 + lane];
            float2 x2 = s2[e2 * 64 + lane];
            float2 x3 = s2[e3 * 64 + lane];
            a0x += p0.x*x0.x; a0y += p0.x*x0.y;
            a1x += p0.y*x0.x; a1y += p0.y*x0.y;
            a2x += p0.z*x0.x; a2y += p0.z*x0.y;
            a3x += p0.w*x0.x; a3y += p0.w*x0.y;
            p1.x *= m1; p1.y *= m1; p1.z *= m1; p1.w *= m1;
            a0x += p1.x*x1.x; a0y += p1.x*x1.y;
            a1x += p1.y*x1.x; a1y += p1.y*x1.y;
            a2x += p1.z*x1.x; a2y += p1.z*x1.y;
            a3x += p1.w*x1.x; a3y += p1.w*x1.y;
            p2.x *= m2; p2.y *= m2; p2.z *= m2; p2.w *= m2;
            a0x += p2.x*x2.x; a0y += p2.x*x2.y;
            a1x += p2.y*x2.x; a1y += p2.y*x2.y;
            a2x += p2.z*x2.x; a2y += p2.z*x2.y;
            a3x += p2.w*x2.x; a3y += p2.w*x2.y;
            p3.x *= m3; p3.y *= m3; p3.z *= m3; p3.w *= m3;
            a0x += p3.x*x3.x; a0y += p3.x*x3.y;
            a1x += p3.y*x3.x; a1y += p3.y*x3.y;
            a2x += p3.z*x3.x; a2y += p3.z*x3.y;
            a3x += p3.w*x3.x; a3y += p3.w*x3.y;
        }
        // normalize (deg==0 -> exact zeros); 1/4 head-mean folded in
        float r0 = 0.25f / (dnm.x + 1e-16f);
        float r1 = 0.25f / (dnm.y + 1e-16f);
        float r2 = 0.25f / (dnm.z + 1e-16f);
        float r3 = 0.25f / (dnm.w + 1e-16f);
        ushort2* grow = (ushort2*)(G16 + (size_t)n * 512);
        ushort2 v;
        v.x = f2bf(a0x * r0); v.y = f2bf(a0y * r0); grow[0 * 64 + lane] = v;
        v.x = f2bf(a1x * r1); v.y = f2bf(a1y * r1); grow[1 * 64 + lane] = v;
        v.x = f2bf(a2x * r2); v.y = f2bf(a2y * r2); grow[2 * 64 + lane] = v;
        v.x = f2bf(a3x * r3); v.y = f2bf(a3y * r3); grow[3 * 64 + lane] = v;
    }
}

// ---------------- K6: out = G16 @ W2T^T via MFMA (LDS-free) ----------------
// A-frag (16x16x32 bf16): lane l holds A[l&15][(l>>4)*8 + 0..7]  (16B contiguous)
// B-frag: lane l holds B[(l>>4)*8 + 0..7][l&15]  -> load row (l&15) of W2T (= col of W2)
// D: col = lane&15, row = (lane>>4)*4 + reg   [m89-verified]
__global__ __launch_bounds__(256)
void k6_gemm(const unsigned short* __restrict__ G16,
             const unsigned short* __restrict__ W2T,
             float* __restrict__ out, int N)
{
    int t = threadIdx.x, lane = t & 63, wv = t >> 6;
    int lr = lane & 15;
    int lk = (lane >> 4) * 8;
    int rbase = blockIdx.x * 128 + wv * 32;   // wave owns 32 rows

    f32x4 acc[2][8];
    #pragma unroll
    for (int mt = 0; mt < 2; ++mt)
        #pragma unroll
        for (int c = 0; c < 8; ++c)
            acc[mt][c] = (f32x4){0.f, 0.f, 0.f, 0.f};

    const unsigned short* a0p = G16 + (size_t)(rbase + lr) * 512 + lk;
    const unsigned short* a1p = a0p + (size_t)16 * 512;
    const unsigned short* bp  = W2T + (size_t)lr * 512 + lk;

    for (int kk = 0; kk < 16; ++kk) {
        short8 a0 = *(const short8*)(a0p + kk * 32);
        short8 a1 = *(const short8*)(a1p + kk * 32);
        #pragma unroll
        for (int c = 0; c < 8; ++c) {
            short8 b = *(const short8*)(bp + (size_t)c * 16 * 512 + kk * 32);
            acc[0][c] = __builtin_amdgcn_mfma_f32_16x16x32_bf16(a0, b, acc[0][c], 0, 0, 0);
            acc[1][c] = __builtin_amdgcn_mfma_f32_16x16x32_bf16(a1, b, acc[1][c], 0, 0, 0);
        }
    }

    int r0 = (lane >> 4) * 4;
    #pragma unroll
    for (int mt = 0; mt < 2; ++mt)
        #pragma unroll
        for (int c = 0; c < 8; ++c)
            #pragma unroll
            for (int i = 0; i < 4; ++i) {
                int m = rbase + mt * 16 + r0 + i;
                if (m < N) out[(size_t)m * 128 + c * 16 + lr] = acc[mt][c][i];
            }
}

extern "C" void kernel_launch(void* const* d_in, const int* in_sizes, int n_in,
                              void* d_out, int out_size, void* d_ws, size_t ws_size,
                              hipStream_t stream)
{
    const float* src     = (const float*)d_in[0];
    const float* dst     = (const float*)d_in[1];
    const int*   eidx    = (const int*)d_in[2];
    const float* Wsrc    = (const float*)d_in[3];
    const float* Wdst    = (const float*)d_in[4];
    const float* att_src = (const float*)d_in[5];
    const float* att_dst = (const float*)d_in[6];

    int E = in_sizes[0] / DIM;          // 200000
    int N = out_size / DIM;             // 50000
    const int* seg = eidx + E;          // edge_index[1]
    int NB = (N + 255) >> 8;

    char* ws = (char*)d_ws;
    size_t o = 0;
    auto alloc = [&](size_t bytes) { size_t r = o; o += (bytes + 255) & ~(size_t)255; return r; };
    // contiguous zero-zone: counts | maxkey | denom
    size_t counts_off = alloc((size_t)(N + 1) * 4);
    size_t maxkey_off = alloc((size_t)N * 4 * 4);
    size_t denom_off  = alloc((size_t)N * 4 * 4);
    int*      counts = (int*)     (ws + counts_off);   // becomes offsets
    unsigned* maxkey = (unsigned*)(ws + maxkey_off);
    float*    denom  = (float*)   (ws + denom_off);
    int zn = (int)((denom_off + (size_t)N * 16 - counts_off) / 4);

    int*            cursor = (int*)           (ws + alloc((size_t)N * 4));
    int*            elist  = (int*)           (ws + alloc((size_t)E * 4));
    int*            bsum   = (int*)           (ws + alloc((size_t)NB * 4));
    float*          a_src  = (float*)         (ws + alloc(512 * 4));
    float*          a_dst  = (float*)         (ws + alloc(512 * 4));
    unsigned short* W2T    = (unsigned short*)(ws + alloc((size_t)65536 * 2));
    float*          alpha  = (float*)         (ws + alloc((size_t)E * 16));   // becomes p
    unsigned short* G16    = (unsigned short*)(ws + alloc((size_t)(N + 128) * 512 * 2));
    (void)ws_size; (void)n_in;

    int zb = (zn + 255) >> 8;
    k0_init<<<zb + 256 + 4, 256, 0, stream>>>(Wsrc, Wdst, att_src, att_dst,
                                              (int*)(ws + counts_off), zn,
                                              a_src, a_dst, W2T, zb);
    k1_alpha<<<1024, 256, 0, stream>>>(src, dst, a_src, a_dst, seg,
                                       alpha, maxkey, counts, E);
    k3a_bsum<<<NB, 256, 0, stream>>>(counts, bsum, N);
    k3b_bscan<<<1, 256, 0, stream>>>(bsum, NB, counts + N);
    k3c_scan<<<NB, 256, 0, stream>>>(counts, cursor, bsum, N);
    k4_scatter<<<(E + 255) / 256, 256, 0, stream>>>(seg, cursor, elist,
                                                    (float4*)alpha, maxkey, denom, E);
    k5a_agg<<<(N + 31) / 32, 256, 0, stream>>>(src, (const float4*)alpha,
                                               counts, elist, denom, G16, N);
    k6_gemm<<<(N + 127) / 128, 256, 0, stream>>>(G16, W2T, (float*)d_out, N);
}